// Round 2
// baseline (625.987 us; speedup 1.0000x reference)
//
#include <hip/hip_runtime.h>
#include <hip/hip_fp16.h>

typedef _Float16 f16;
typedef __attribute__((ext_vector_type(8))) _Float16 f16x8;
typedef __attribute__((ext_vector_type(4))) _Float16 f16x4;
typedef __attribute__((ext_vector_type(2))) _Float16 f16x2;
typedef __attribute__((ext_vector_type(4))) float f32x4;

#define AS1(p) ((__attribute__((address_space(1))) char*)(p))
#define AS3(p) ((__attribute__((address_space(3))) char*)(p))

static __device__ __forceinline__ float wave_red_sum(float v) {
#pragma unroll
  for (int m = 1; m < 64; m <<= 1) v += __shfl_xor(v, m);
  return v;
}
static __device__ __forceinline__ float wave_red_max(float v) {
#pragma unroll
  for (int m = 1; m < 64; m <<= 1) v = fmaxf(v, __shfl_xor(v, m));
  return v;
}

// ---------------- weight scale: sum |W| (deterministic 2-stage) ----------------
__global__ __launch_bounds__(256) void absum_partial(
    const float* __restrict__ Wq, const float* __restrict__ Wk,
    const float* __restrict__ Wv, const float* __restrict__ Wo,
    float* __restrict__ partial) {
  const int w = blockIdx.x >> 8;   // 0..3
  const int lb = blockIdx.x & 255;
  const float* W = (w == 0) ? Wq : (w == 1) ? Wk : (w == 2) ? Wv : Wo;
  const int per_block = (w == 0) ? (4194304 >> 8) : (1048576 >> 8);
  const float* base = W + (size_t)lb * per_block;
  float s = 0.f;
  for (int i = threadIdx.x * 4; i < per_block; i += 256 * 4) {
    float4 v = *(const float4*)(base + i);
    s += fabsf(v.x) + fabsf(v.y) + fabsf(v.z) + fabsf(v.w);
  }
  s = wave_red_sum(s);
  __shared__ float red[4];
  const int wave = threadIdx.x >> 6, lane = threadIdx.x & 63;
  if (lane == 0) red[wave] = s;
  __syncthreads();
  if (threadIdx.x == 0) partial[blockIdx.x] = red[0] + red[1] + red[2] + red[3];
}

__global__ __launch_bounds__(256) void absum_final(const float* __restrict__ partial,
                                                   float* __restrict__ scales) {
  const int wave = threadIdx.x >> 6, lane = threadIdx.x & 63;
  const float* p = partial + wave * 256;
  float s = p[lane] + p[lane + 64] + p[lane + 128] + p[lane + 192];
  s = wave_red_sum(s);
  if (lane == 0) {
    const float cnt = (wave == 0) ? 4194304.f : 1048576.f;
    const float mean = s / cnt;
    const float mul = 1.0f / fmaxf(mean, 1e-5f);  // reference: scale = 1/clip(mean,1e-5)
    scales[wave] = mul;
    scales[4 + wave] = 1.0f / mul;                // reference dequant: t / scale
  }
}

// ---------------- ternary weight quantization ----------------
__global__ __launch_bounds__(256) void quant_w_ternary(const float* __restrict__ W,
                                                       f16* __restrict__ W8,
                                                       const float* __restrict__ scales,
                                                       int widx, int n) {
  const float mul = scales[widx];
  const int i = (blockIdx.x * 256 + threadIdx.x) * 4;
  if (i >= n) return;
  float4 v = *(const float4*)(W + i);
  f16x4 o;
  o[0] = (f16)fminf(fmaxf(rintf(v.x * mul), -1.f), 1.f);
  o[1] = (f16)fminf(fmaxf(rintf(v.y * mul), -1.f), 1.f);
  o[2] = (f16)fminf(fmaxf(rintf(v.z * mul), -1.f), 1.f);
  o[3] = (f16)fminf(fmaxf(rintf(v.w * mul), -1.f), 1.f);
  *(f16x4*)(W8 + i) = o;
}

// Wq with the attention group-sum folded in: We[h*128+d][e] = sum_g tern(Wq[(h*4+g)*128+d][e])
__global__ __launch_bounds__(256) void quant_wq_eff(const float* __restrict__ Wq,
                                                    f16* __restrict__ We,
                                                    const float* __restrict__ scales) {
  const float mul = scales[0];
  const int idx = (blockIdx.x * 256 + threadIdx.x) * 4;  // over 512*2048
  const int j = idx >> 11, e = idx & 2047;
  const int h = j >> 7, d = j & 127;
  float a0 = 0, a1 = 0, a2 = 0, a3 = 0;
#pragma unroll
  for (int g = 0; g < 4; g++) {
    const float* src = Wq + (size_t)((h * 4 + g) * 128 + d) * 2048 + e;
    float4 v = *(const float4*)src;
    a0 += fminf(fmaxf(rintf(v.x * mul), -1.f), 1.f);
    a1 += fminf(fmaxf(rintf(v.y * mul), -1.f), 1.f);
    a2 += fminf(fmaxf(rintf(v.z * mul), -1.f), 1.f);
    a3 += fminf(fmaxf(rintf(v.w * mul), -1.f), 1.f);
  }
  f16x4 o; o[0] = (f16)a0; o[1] = (f16)a1; o[2] = (f16)a2; o[3] = (f16)a3;
  *(f16x4*)(We + idx) = o;
}

__global__ void bq_eff_kernel(const float* __restrict__ bq, float* __restrict__ be) {
  const int j = blockIdx.x * 256 + threadIdx.x;
  if (j >= 512) return;
  const int h = j >> 7, d = j & 127;
  float s = 0.f;
#pragma unroll
  for (int g = 0; g < 4; g++) s += bq[(h * 4 + g) * 128 + d];
  be[j] = s;
}

// ---------------- per-token activation quantization (cols = 2048) ----------------
__global__ __launch_bounds__(256) void quant_act(const float* __restrict__ X,
                                                 f16* __restrict__ Q,
                                                 float* __restrict__ deq) {
  const size_t tok = blockIdx.x;
  const float* x = X + tok * 2048;
  const int t = threadIdx.x;
  float4 v0 = *(const float4*)(x + t * 8);
  float4 v1 = *(const float4*)(x + t * 8 + 4);
  float amax = fmaxf(fmaxf(fmaxf(fabsf(v0.x), fabsf(v0.y)), fmaxf(fabsf(v0.z), fabsf(v0.w))),
                     fmaxf(fmaxf(fabsf(v1.x), fabsf(v1.y)), fmaxf(fabsf(v1.z), fabsf(v1.w))));
  amax = wave_red_max(amax);
  __shared__ float red[4];
  const int wave = t >> 6, lane = t & 63;
  if (lane == 0) red[wave] = amax;
  __syncthreads();
  amax = fmaxf(fmaxf(red[0], red[1]), fmaxf(red[2], red[3]));
  const float scale = 127.0f / fmaxf(amax, 1e-5f);
  f16x8 q;
  q[0] = (f16)fminf(fmaxf(rintf(v0.x * scale), -128.f), 127.f);
  q[1] = (f16)fminf(fmaxf(rintf(v0.y * scale), -128.f), 127.f);
  q[2] = (f16)fminf(fmaxf(rintf(v0.z * scale), -128.f), 127.f);
  q[3] = (f16)fminf(fmaxf(rintf(v0.w * scale), -128.f), 127.f);
  q[4] = (f16)fminf(fmaxf(rintf(v1.x * scale), -128.f), 127.f);
  q[5] = (f16)fminf(fmaxf(rintf(v1.y * scale), -128.f), 127.f);
  q[6] = (f16)fminf(fmaxf(rintf(v1.z * scale), -128.f), 127.f);
  q[7] = (f16)fminf(fmaxf(rintf(v1.w * scale), -128.f), 127.f);
  *(f16x8*)(Q + tok * 2048 + t * 8) = q;
  if (t == 0) deq[tok] = 1.0f / scale;
}

// ---------------- GEMM: C[M,N] = (A[M,K] . W[N,K]^T) * deqA[i]*deqW + bias[j], m97 structure ----------------
template <typename OutT>
__global__ __launch_bounds__(256) void gemm_bt_deq(
    const f16* __restrict__ A, const f16* __restrict__ W,
    const float* __restrict__ deqA, const float* __restrict__ scales, int deq_idx,
    const float* __restrict__ bias, OutT* __restrict__ C,
    int M, int N, int K, float out_scale) {
  __shared__ f16 As[128 * 32];
  __shared__ f16 Bs[128 * 32];
  const int t = threadIdx.x;
  const int wave = t >> 6, lane = t & 63;
  const int lg = lane >> 4, ln = lane & 15;
  const int bm = blockIdx.y, bn = blockIdx.x;
  const int wr = (wave >> 1) * 64, wc = (wave & 1) * 64;
  f32x4 acc[4][4] = {};
  const f16* gA = A + (size_t)(bm * 128 + (t >> 2)) * K + (t & 3) * 8;
  const f16* gB = W + (size_t)(bn * 128 + (t >> 2)) * K + (t & 3) * 8;
  const int wb = wave * 1024;  // per-wave byte offset inside each 4096B issue segment

  for (int k0 = 0; k0 < K; k0 += 32) {
    __builtin_amdgcn_global_load_lds(AS1(gA + k0), AS3((char*)As + wb), 16, 0, 0);
    __builtin_amdgcn_global_load_lds(AS1(gA + (size_t)64 * K + k0), AS3((char*)As + 4096 + wb), 16, 0, 0);
    __builtin_amdgcn_global_load_lds(AS1(gB + k0), AS3((char*)Bs + wb), 16, 0, 0);
    __builtin_amdgcn_global_load_lds(AS1(gB + (size_t)64 * K + k0), AS3((char*)Bs + 4096 + wb), 16, 0, 0);
    __syncthreads();
    f16x8 af[4], bf[4];
#pragma unroll
    for (int fr = 0; fr < 4; fr++) af[fr] = *(const f16x8*)(As + (wr + fr * 16 + ln) * 32 + lg * 8);
#pragma unroll
    for (int fc = 0; fc < 4; fc++) bf[fc] = *(const f16x8*)(Bs + (wc + fc * 16 + ln) * 32 + lg * 8);
#pragma unroll
    for (int fr = 0; fr < 4; fr++)
#pragma unroll
      for (int fc = 0; fc < 4; fc++)
        acc[fr][fc] = __builtin_amdgcn_mfma_f32_16x16x32_f16(af[fr], bf[fc], acc[fr][fc], 0, 0, 0);
    __syncthreads();
  }
  const float dW = scales[deq_idx];
#pragma unroll
  for (int fr = 0; fr < 4; fr++) {
#pragma unroll
    for (int r = 0; r < 4; r++) {
      const int grow = bm * 128 + wr + fr * 16 + lg * 4 + r;
      const float dA = deqA[grow] * dW;
#pragma unroll
      for (int fc = 0; fc < 4; fc++) {
        const int gcol = bn * 128 + wc + fc * 16 + ln;
        const float y = (acc[fr][fc][r] * dA + bias[gcol]) * out_scale;
        C[(size_t)grow * N + gcol] = (OutT)y;
      }
    }
  }
}

// ---------------- flash attention, 4 kv heads, group-summed q, causal ----------------
// Qs/Kq/Vq layout: [B, S, KH*HD] = [B*2048, 512], head h at col h*128. X out f32 same layout.
__global__ __launch_bounds__(256) void attn_kernel(
    const f16* __restrict__ Qs, const f16* __restrict__ Kq, const f16* __restrict__ Vq,
    float* __restrict__ X) {
  __shared__ f16 Ks[64 * 128];
  __shared__ f16 Vs[128 * 72];      // transposed V, padded stride 72 (144B, 16B-aligned)
  __shared__ f16 Ps[4][16 * 72];    // per-wave P tile
  const int qt = blockIdx.x, bh = blockIdx.y;
  const int b = bh >> 2, h = bh & 3;
  const int t = threadIdx.x, wave = t >> 6, lane = t & 63;
  const int lg = lane >> 4, ln = lane & 15;
  const size_t base = (size_t)b * 2048 * 512 + h * 128;

  f16x8 qf[4];
  {
    const int qrow = qt * 64 + wave * 16 + ln;
    const f16* qp = Qs + base + (size_t)qrow * 512 + lg * 8;
#pragma unroll
    for (int ks = 0; ks < 4; ks++) qf[ks] = *(const f16x8*)(qp + ks * 32);
  }
  f32x4 o[8] = {};
  float m_r[4], l_r[4];
#pragma unroll
  for (int r = 0; r < 4; r++) { m_r[r] = -1e30f; l_r[r] = 0.f; }
  const int vsp = (t >> 3) * 2, vdp = (t & 7) * 16;

  for (int s0 = 0; s0 <= qt * 64; s0 += 64) {
    // V tile -> regs (global reads, no LDS hazard yet)
    const f16* gV = Vq + base + (size_t)(s0 + vsp) * 512 + vdp;
    f16x8 va0 = *(const f16x8*)(gV);
    f16x8 va1 = *(const f16x8*)(gV + 8);
    f16x8 vb0 = *(const f16x8*)(gV + 512);
    f16x8 vb1 = *(const f16x8*)(gV + 520);
    __syncthreads();  // all waves done with previous tile's LDS
    // K tile -> LDS (async direct)
    const f16* gK = Kq + base + (size_t)(s0 + (t >> 4)) * 512 + (t & 15) * 8;
#pragma unroll
    for (int i = 0; i < 4; i++)
      __builtin_amdgcn_global_load_lds(AS1(gK + (size_t)i * 16 * 512),
                                       AS3((char*)Ks + i * 4096 + wave * 1024), 16, 0, 0);
    // V transpose -> LDS
#pragma unroll
    for (int j = 0; j < 8; j++) {
      f16x2 p0; p0[0] = va0[j]; p0[1] = vb0[j];
      *(f16x2*)(Vs + (vdp + j) * 72 + vsp) = p0;
      f16x2 p1; p1[0] = va1[j]; p1[1] = vb1[j];
      *(f16x2*)(Vs + (vdp + 8 + j) * 72 + vsp) = p1;
    }
    __syncthreads();  // staging visible (vmcnt+lgkm drained by barrier)

    // S = Q K^T  (16 q-rows x 64 kv-cols per wave)
    f32x4 sacc[4] = {};
#pragma unroll
    for (int ks = 0; ks < 4; ks++)
#pragma unroll
      for (int fc = 0; fc < 4; fc++) {
        f16x8 bf = *(const f16x8*)(Ks + (fc * 16 + ln) * 128 + ks * 32 + lg * 8);
        sacc[fc] = __builtin_amdgcn_mfma_f32_16x16x32_f16(qf[ks], bf, sacc[fc], 0, 0, 0);
      }
    if (s0 == qt * 64) {  // diagonal tile: causal mask
      const int rbase = qt * 64 + wave * 16 + lg * 4;
#pragma unroll
      for (int fc = 0; fc < 4; fc++) {
        const int col = s0 + fc * 16 + ln;
#pragma unroll
        for (int r = 0; r < 4; r++)
          if (col > rbase + r) sacc[fc][r] = -1e30f;
      }
    }
    // online softmax (rows live across the 16-lane group)
    float tm[4];
#pragma unroll
    for (int r = 0; r < 4; r++)
      tm[r] = fmaxf(fmaxf(sacc[0][r], sacc[1][r]), fmaxf(sacc[2][r], sacc[3][r]));
#pragma unroll
    for (int r = 0; r < 4; r++) {
#pragma unroll
      for (int msk = 1; msk < 16; msk <<= 1) tm[r] = fmaxf(tm[r], __shfl_xor(tm[r], msk));
    }
    float al[4], ps[4];
#pragma unroll
    for (int r = 0; r < 4; r++) {
      const float mn = fmaxf(m_r[r], tm[r]);
      al[r] = __expf(m_r[r] - mn);
      m_r[r] = mn;
      ps[r] = 0.f;
    }
#pragma unroll
    for (int fc = 0; fc < 4; fc++)
#pragma unroll
      for (int r = 0; r < 4; r++) {
        const float p = __expf(sacc[fc][r] - m_r[r]);
        ps[r] += p;
        Ps[wave][(lg * 4 + r) * 72 + fc * 16 + ln] = (f16)p;
      }
#pragma unroll
    for (int r = 0; r < 4; r++) {
#pragma unroll
      for (int msk = 1; msk < 16; msk <<= 1) ps[r] += __shfl_xor(ps[r], msk);
      l_r[r] = l_r[r] * al[r] + ps[r];
    }
#pragma unroll
    for (int fc2 = 0; fc2 < 8; fc2++)
#pragma unroll
      for (int r = 0; r < 4; r++) o[fc2][r] *= al[r];
    // PV: O += P[16x64] . V[64x128]
#pragma unroll
    for (int ks2 = 0; ks2 < 2; ks2++) {
      f16x8 pa = *(const f16x8*)(&Ps[wave][ln * 72 + ks2 * 32 + lg * 8]);
#pragma unroll
      for (int fc2 = 0; fc2 < 8; fc2++) {
        f16x8 vbf = *(const f16x8*)(Vs + (fc2 * 16 + ln) * 72 + ks2 * 32 + lg * 8);
        o[fc2] = __builtin_amdgcn_mfma_f32_16x16x32_f16(pa, vbf, o[fc2], 0, 0, 0);
      }
    }
  }
  const int rbase = qt * 64 + wave * 16 + lg * 4;
#pragma unroll
  for (int r = 0; r < 4; r++) {
    const float inv = 1.0f / l_r[r];
    float* xp = X + ((size_t)b * 2048 + rbase + r) * 512 + h * 128 + ln;
#pragma unroll
    for (int fc2 = 0; fc2 < 8; fc2++) xp[fc2 * 16] = o[fc2][r] * inv;
  }
}

// ---------------- LayerNorm(512) + act_quant fused ----------------
__global__ __launch_bounds__(256) void ln_quant(const float* __restrict__ X,
                                                const float* __restrict__ gamma,
                                                const float* __restrict__ beta,
                                                f16* __restrict__ Q, float* __restrict__ deq) {
  const size_t tok = blockIdx.x;
  const int t = threadIdx.x;
  const float* x = X + tok * 512;
  float2 v = *(const float2*)(x + t * 2);
  float s = v.x + v.y, sq = v.x * v.x + v.y * v.y;
  s = wave_red_sum(s);
  sq = wave_red_sum(sq);
  __shared__ float rs[4], rq[4], rm[4];
  const int wave = t >> 6, lane = t & 63;
  if (lane == 0) { rs[wave] = s; rq[wave] = sq; }
  __syncthreads();
  s = rs[0] + rs[1] + rs[2] + rs[3];
  sq = rq[0] + rq[1] + rq[2] + rq[3];
  const float mean = s * (1.0f / 512.0f);
  const float var = sq * (1.0f / 512.0f) - mean * mean;
  const float inv = 1.0f / sqrtf(var + 1e-5f);
  float2 g = *(const float2*)(gamma + t * 2);
  float2 be = *(const float2*)(beta + t * 2);
  const float t0 = (v.x - mean) * inv * g.x + be.x;
  const float t1 = (v.y - mean) * inv * g.y + be.y;
  float amax = fmaxf(fabsf(t0), fabsf(t1));
  amax = wave_red_max(amax);
  if (lane == 0) rm[wave] = amax;
  __syncthreads();
  amax = fmaxf(fmaxf(rm[0], rm[1]), fmaxf(rm[2], rm[3]));
  const float scale = 127.0f / fmaxf(amax, 1e-5f);
  f16x2 q;
  q[0] = (f16)fminf(fmaxf(rintf(t0 * scale), -128.f), 127.f);
  q[1] = (f16)fminf(fmaxf(rintf(t1 * scale), -128.f), 127.f);
  *(f16x2*)(Q + tok * 512 + t * 2) = q;
  if (t == 0) deq[tok] = 1.0f / scale;
}

// ---------------- launch ----------------
extern "C" void kernel_launch(void* const* d_in, const int* in_sizes, int n_in,
                              void* d_out, int out_size, void* d_ws, size_t ws_size,
                              hipStream_t stream) {
  const float* query = (const float*)d_in[0];
  const float* key   = (const float*)d_in[1];
  const float* value = (const float*)d_in[2];
  const float* Wq = (const float*)d_in[3];
  const float* bq = (const float*)d_in[4];
  const float* Wk = (const float*)d_in[5];
  const float* bk = (const float*)d_in[6];
  const float* Wv = (const float*)d_in[7];
  const float* bv = (const float*)d_in[8];
  const float* Wo = (const float*)d_in[9];
  const float* bo = (const float*)d_in[10];
  const float* gamma = (const float*)d_in[11];
  const float* beta  = (const float*)d_in[12];

  char* ws = (char*)d_ws;
  size_t off = 0;
  auto alloc = [&](size_t bytes) {
    char* p = ws + off;
    off = (off + bytes + 255) & ~(size_t)255;
    return p;
  };
  float* partial = (float*)alloc(1024 * 4);
  float* scales  = (float*)alloc(8 * 4);
  float* bqe     = (float*)alloc(512 * 4);
  f16* Wqe = (f16*)alloc((size_t)512 * 2048 * 2);
  f16* Wk8 = (f16*)alloc((size_t)512 * 2048 * 2);
  f16* Wv8 = (f16*)alloc((size_t)512 * 2048 * 2);
  f16* Wo8 = (f16*)alloc((size_t)2048 * 512 * 2);
  f16* a8  = (f16*)alloc((size_t)8192 * 2048 * 2);
  float* deqA  = (float*)alloc(8192 * 4);
  float* deqO  = (float*)alloc(8192 * 4);
  f16* qs = (f16*)alloc((size_t)8192 * 512 * 2);
  f16* kq = (f16*)alloc((size_t)8192 * 512 * 2);
  f16* vq = (f16*)alloc((size_t)8192 * 512 * 2);
  float* x = (float*)alloc((size_t)8192 * 512 * 4);
  f16* a8o = (f16*)alloc((size_t)8192 * 512 * 2);
  (void)ws_size; (void)in_sizes; (void)n_in; (void)out_size;

  // weight scales + quantization
  absum_partial<<<1024, 256, 0, stream>>>(Wq, Wk, Wv, Wo, partial);
  absum_final<<<1, 256, 0, stream>>>(partial, scales);
  quant_wq_eff<<<1024, 256, 0, stream>>>(Wq, Wqe, scales);
  bq_eff_kernel<<<2, 256, 0, stream>>>(bq, bqe);
  quant_w_ternary<<<1024, 256, 0, stream>>>(Wk, Wk8, scales, 1, 1048576);
  quant_w_ternary<<<1024, 256, 0, stream>>>(Wv, Wv8, scales, 2, 1048576);
  quant_w_ternary<<<1024, 256, 0, stream>>>(Wo, Wo8, scales, 3, 1048576);

  // projections (a8 buffer reused sequentially)
  quant_act<<<8192, 256, 0, stream>>>(query, a8, deqA);
  gemm_bt_deq<f16><<<dim3(4, 64), 256, 0, stream>>>(a8, Wqe, deqA, scales, 4 + 0, bqe, qs,
                                                    8192, 512, 2048, 1.0f / 128.0f);
  quant_act<<<8192, 256, 0, stream>>>(key, a8, deqA);
  gemm_bt_deq<f16><<<dim3(4, 64), 256, 0, stream>>>(a8, Wk8, deqA, scales, 4 + 1, bk, kq,
                                                    8192, 512, 2048, 1.0f);
  quant_act<<<8192, 256, 0, stream>>>(value, a8, deqA);
  gemm_bt_deq<f16><<<dim3(4, 64), 256, 0, stream>>>(a8, Wv8, deqA, scales, 4 + 2, bv, vq,
                                                    8192, 512, 2048, 1.0f);

  // attention
  attn_kernel<<<dim3(32, 16), 256, 0, stream>>>(qs, kq, vq, x);

  // layernorm + quant + output projection
  ln_quant<<<8192, 256, 0, stream>>>(x, gamma, beta, a8o, deqO);
  gemm_bt_deq<float><<<dim3(16, 64), 256, 0, stream>>>(a8o, Wo8, deqO, scales, 4 + 3, bo,
                                                       (float*)d_out, 8192, 2048, 512, 1.0f);
}

// Round 3
// 484.369 us; speedup vs baseline: 1.2924x; 1.2924x over previous
//
#include <hip/hip_runtime.h>
#include <hip/hip_fp16.h>

typedef _Float16 f16;
typedef __attribute__((ext_vector_type(8))) _Float16 f16x8;
typedef __attribute__((ext_vector_type(4))) _Float16 f16x4;
typedef __attribute__((ext_vector_type(2))) _Float16 f16x2;
typedef __attribute__((ext_vector_type(4))) float f32x4;

#define AS1(p) ((__attribute__((address_space(1))) char*)(p))
#define AS3(p) ((__attribute__((address_space(3))) char*)(p))

static __device__ __forceinline__ float wave_red_sum(float v) {
#pragma unroll
  for (int m = 1; m < 64; m <<= 1) v += __shfl_xor(v, m);
  return v;
}
static __device__ __forceinline__ float wave_red_max(float v) {
#pragma unroll
  for (int m = 1; m < 64; m <<= 1) v = fmaxf(v, __shfl_xor(v, m));
  return v;
}

// ---------------- weight scale: sum |W| (deterministic 2-stage) ----------------
__global__ __launch_bounds__(256) void absum_partial(
    const float* __restrict__ Wq, const float* __restrict__ Wk,
    const float* __restrict__ Wv, const float* __restrict__ Wo,
    float* __restrict__ partial) {
  const int w = blockIdx.x >> 8;
  const int lb = blockIdx.x & 255;
  const float* W = (w == 0) ? Wq : (w == 1) ? Wk : (w == 2) ? Wv : Wo;
  const int per_block = (w == 0) ? (4194304 >> 8) : (1048576 >> 8);
  const float* base = W + (size_t)lb * per_block;
  float s = 0.f;
  for (int i = threadIdx.x * 4; i < per_block; i += 256 * 4) {
    float4 v = *(const float4*)(base + i);
    s += fabsf(v.x) + fabsf(v.y) + fabsf(v.z) + fabsf(v.w);
  }
  s = wave_red_sum(s);
  __shared__ float red[4];
  const int wave = threadIdx.x >> 6, lane = threadIdx.x & 63;
  if (lane == 0) red[wave] = s;
  __syncthreads();
  if (threadIdx.x == 0) partial[blockIdx.x] = red[0] + red[1] + red[2] + red[3];
}

__global__ __launch_bounds__(256) void absum_final(const float* __restrict__ partial,
                                                   float* __restrict__ scales) {
  const int wave = threadIdx.x >> 6, lane = threadIdx.x & 63;
  const float* p = partial + wave * 256;
  float s = p[lane] + p[lane + 64] + p[lane + 128] + p[lane + 192];
  s = wave_red_sum(s);
  if (lane == 0) {
    const float cnt = (wave == 0) ? 4194304.f : 1048576.f;
    const float mean = s / cnt;
    const float mul = 1.0f / fmaxf(mean, 1e-5f);
    scales[wave] = mul;
    scales[4 + wave] = 1.0f / mul;
  }
}

// ---------------- ternary weight quantization ----------------
__global__ __launch_bounds__(256) void quant_w_ternary(const float* __restrict__ W,
                                                       f16* __restrict__ W8,
                                                       const float* __restrict__ scales,
                                                       int widx, int n) {
  const float mul = scales[widx];
  const int i = (blockIdx.x * 256 + threadIdx.x) * 4;
  if (i >= n) return;
  float4 v = *(const float4*)(W + i);
  f16x4 o;
  o[0] = (f16)fminf(fmaxf(rintf(v.x * mul), -1.f), 1.f);
  o[1] = (f16)fminf(fmaxf(rintf(v.y * mul), -1.f), 1.f);
  o[2] = (f16)fminf(fmaxf(rintf(v.z * mul), -1.f), 1.f);
  o[3] = (f16)fminf(fmaxf(rintf(v.w * mul), -1.f), 1.f);
  *(f16x4*)(W8 + i) = o;
}

// Wq with group-sum folded: We[h*128+d][e] = sum_g tern(Wq[(h*4+g)*128+d][e])
__global__ __launch_bounds__(256) void quant_wq_eff(const float* __restrict__ Wq,
                                                    f16* __restrict__ We,
                                                    const float* __restrict__ scales) {
  const float mul = scales[0];
  const int idx = (blockIdx.x * 256 + threadIdx.x) * 4;
  const int j = idx >> 11, e = idx & 2047;
  const int h = j >> 7, d = j & 127;
  float a0 = 0, a1 = 0, a2 = 0, a3 = 0;
#pragma unroll
  for (int g = 0; g < 4; g++) {
    const float* src = Wq + (size_t)((h * 4 + g) * 128 + d) * 2048 + e;
    float4 v = *(const float4*)src;
    a0 += fminf(fmaxf(rintf(v.x * mul), -1.f), 1.f);
    a1 += fminf(fmaxf(rintf(v.y * mul), -1.f), 1.f);
    a2 += fminf(fmaxf(rintf(v.z * mul), -1.f), 1.f);
    a3 += fminf(fmaxf(rintf(v.w * mul), -1.f), 1.f);
  }
  f16x4 o; o[0] = (f16)a0; o[1] = (f16)a1; o[2] = (f16)a2; o[3] = (f16)a3;
  *(f16x4*)(We + idx) = o;
}

__global__ void bq_eff_kernel(const float* __restrict__ bq, float* __restrict__ be) {
  const int j = blockIdx.x * 256 + threadIdx.x;
  if (j >= 512) return;
  const int h = j >> 7, d = j & 127;
  float s = 0.f;
#pragma unroll
  for (int g = 0; g < 4; g++) s += bq[(h * 4 + g) * 128 + d];
  be[j] = s;
}

// ---------------- per-token activation quantization, 3 tensors fused ----------------
__global__ __launch_bounds__(256) void quant_act3(
    const float* __restrict__ Xq, const float* __restrict__ Xk, const float* __restrict__ Xv,
    f16* __restrict__ Aq, f16* __restrict__ Ak, f16* __restrict__ Av,
    float* __restrict__ deq3) {
  const int which = blockIdx.y;
  const float* X = which == 0 ? Xq : which == 1 ? Xk : Xv;
  f16* Q = which == 0 ? Aq : which == 1 ? Ak : Av;
  float* deq = deq3 + which * 8192;
  const size_t tok = blockIdx.x;
  const float* x = X + tok * 2048;
  const int t = threadIdx.x;
  float4 v0 = *(const float4*)(x + t * 8);
  float4 v1 = *(const float4*)(x + t * 8 + 4);
  float amax = fmaxf(fmaxf(fmaxf(fabsf(v0.x), fabsf(v0.y)), fmaxf(fabsf(v0.z), fabsf(v0.w))),
                     fmaxf(fmaxf(fabsf(v1.x), fabsf(v1.y)), fmaxf(fabsf(v1.z), fabsf(v1.w))));
  amax = wave_red_max(amax);
  __shared__ float red[4];
  const int wave = t >> 6, lane = t & 63;
  if (lane == 0) red[wave] = amax;
  __syncthreads();
  amax = fmaxf(fmaxf(red[0], red[1]), fmaxf(red[2], red[3]));
  const float scale = 127.0f / fmaxf(amax, 1e-5f);
  f16x8 q;
  q[0] = (f16)fminf(fmaxf(rintf(v0.x * scale), -128.f), 127.f);
  q[1] = (f16)fminf(fmaxf(rintf(v0.y * scale), -128.f), 127.f);
  q[2] = (f16)fminf(fmaxf(rintf(v0.z * scale), -128.f), 127.f);
  q[3] = (f16)fminf(fmaxf(rintf(v0.w * scale), -128.f), 127.f);
  q[4] = (f16)fminf(fmaxf(rintf(v1.x * scale), -128.f), 127.f);
  q[5] = (f16)fminf(fmaxf(rintf(v1.y * scale), -128.f), 127.f);
  q[6] = (f16)fminf(fmaxf(rintf(v1.z * scale), -128.f), 127.f);
  q[7] = (f16)fminf(fmaxf(rintf(v1.w * scale), -128.f), 127.f);
  *(f16x8*)(Q + tok * 2048 + t * 8) = q;
  if (t == 0) deq[tok] = 1.0f / scale;
}

// ---------------- GEMM core: C[.,N] tile (bm,bn), A[M,K].W[N,K]^T ----------------
template <typename OutT>
static __device__ __forceinline__ void gemm_core(
    const f16* __restrict__ A, const f16* __restrict__ W,
    const float* __restrict__ deqA, const float dW,
    const float* __restrict__ bias, OutT* __restrict__ C,
    const int N, const int K, const float out_scale, const int bm, const int bn,
    f16* __restrict__ As, f16* __restrict__ Bs) {
  const int t = threadIdx.x;
  const int wave = t >> 6, lane = t & 63;
  const int lg = lane >> 4, ln = lane & 15;
  const int wr = (wave >> 1) * 64, wc = (wave & 1) * 64;
  f32x4 acc[4][4] = {};
  const f16* gA = A + (size_t)(bm * 128 + (t >> 2)) * K + (t & 3) * 8;
  const f16* gB = W + (size_t)(bn * 128 + (t >> 2)) * K + (t & 3) * 8;
  const int wb = wave * 1024;

  for (int k0 = 0; k0 < K; k0 += 32) {
    __builtin_amdgcn_global_load_lds(AS1(gA + k0), AS3((char*)As + wb), 16, 0, 0);
    __builtin_amdgcn_global_load_lds(AS1(gA + (size_t)64 * K + k0), AS3((char*)As + 4096 + wb), 16, 0, 0);
    __builtin_amdgcn_global_load_lds(AS1(gB + k0), AS3((char*)Bs + wb), 16, 0, 0);
    __builtin_amdgcn_global_load_lds(AS1(gB + (size_t)64 * K + k0), AS3((char*)Bs + 4096 + wb), 16, 0, 0);
    __syncthreads();
    f16x8 af[4], bf[4];
#pragma unroll
    for (int fr = 0; fr < 4; fr++) af[fr] = *(const f16x8*)(As + (wr + fr * 16 + ln) * 32 + lg * 8);
#pragma unroll
    for (int fc = 0; fc < 4; fc++) bf[fc] = *(const f16x8*)(Bs + (wc + fc * 16 + ln) * 32 + lg * 8);
    __builtin_amdgcn_s_setprio(1);
#pragma unroll
    for (int fr = 0; fr < 4; fr++)
#pragma unroll
      for (int fc = 0; fc < 4; fc++)
        acc[fr][fc] = __builtin_amdgcn_mfma_f32_16x16x32_f16(af[fr], bf[fc], acc[fr][fc], 0, 0, 0);
    __builtin_amdgcn_s_setprio(0);
    __syncthreads();
  }
#pragma unroll
  for (int fr = 0; fr < 4; fr++) {
#pragma unroll
    for (int r = 0; r < 4; r++) {
      const int grow = bm * 128 + wr + fr * 16 + lg * 4 + r;
      const float dA = deqA[grow] * dW;
#pragma unroll
      for (int fc = 0; fc < 4; fc++) {
        const int gcol = bn * 128 + wc + fc * 16 + ln;
        const float y = (acc[fr][fc][r] * dA + bias[gcol]) * out_scale;
        C[(size_t)grow * N + gcol] = (OutT)y;
      }
    }
  }
}

// fused QKV projection: grid (4, 64, 3), XCD-chunked remap (768 blocks, 96/XCD)
__global__ __launch_bounds__(256) void gemm_qkv(
    const f16* __restrict__ Aq, const f16* __restrict__ Ak, const f16* __restrict__ Av,
    const f16* __restrict__ Wqe, const f16* __restrict__ Wk8, const f16* __restrict__ Wv8,
    const float* __restrict__ deq3, const float* __restrict__ scales,
    const float* __restrict__ bqe, const float* __restrict__ bk, const float* __restrict__ bv,
    f16* __restrict__ Cq, f16* __restrict__ Ck, f16* __restrict__ Cv) {
  __shared__ f16 As[128 * 32];
  __shared__ f16 Bs[128 * 32];
  const int orig = blockIdx.x + (blockIdx.y << 2) + (blockIdx.z << 8);
  const int wk = ((orig & 7) * 96) + (orig >> 3);
  const int z = wk >> 8, rem = wk & 255, bm = rem >> 2, bn = rem & 3;
  const f16* A = z == 0 ? Aq : z == 1 ? Ak : Av;
  const f16* W = z == 0 ? Wqe : z == 1 ? Wk8 : Wv8;
  const float* bias = z == 0 ? bqe : z == 1 ? bk : bv;
  f16* C = z == 0 ? Cq : z == 1 ? Ck : Cv;
  gemm_core<f16>(A, W, deq3 + z * 8192, scales[4 + z], bias, C,
                 512, 2048, z == 0 ? (1.0f / 128.0f) : 1.0f, bm, bn, As, Bs);
}

// output projection: grid (16, 64), remap (1024 blocks, 128/XCD)
__global__ __launch_bounds__(256) void gemm_o(
    const f16* __restrict__ A, const f16* __restrict__ W,
    const float* __restrict__ deqA, const float* __restrict__ scales,
    const float* __restrict__ bias, float* __restrict__ C) {
  __shared__ f16 As[128 * 32];
  __shared__ f16 Bs[128 * 32];
  const int orig = blockIdx.x + (blockIdx.y << 4);
  const int wk = ((orig & 7) * 128) + (orig >> 3);
  const int bm = wk >> 4, bn = wk & 15;
  gemm_core<float>(A, W, deqA, scales[7], bias, C, 2048, 512, 1.0f, bm, bn, As, Bs);
}

// ---------------- flash attention helpers ----------------
static __device__ __forceinline__ void stage_k(char* ksb, const f16* src, int wave) {
#pragma unroll
  for (int i = 0; i < 4; i++)
    __builtin_amdgcn_global_load_lds(AS1(src + (size_t)i * 16 * 512),
                                     AS3(ksb + i * 4096 + wave * 1024), 16, 0, 0);
}

static __device__ __forceinline__ void write_v(f16* vsb, int vsp, int vdp,
                                               f16x8 va0, f16x8 va1, f16x8 vb0, f16x8 vb1) {
#pragma unroll
  for (int j = 0; j < 8; j++) {
    const int d0 = vdp + j;
    const int m0 = ((d0 ^ (d0 >> 4)) & 7) << 3;
    f16x2 p0; p0[0] = va0[j]; p0[1] = vb0[j];
    *(f16x2*)(vsb + d0 * 64 + (vsp ^ m0)) = p0;
    const int d1 = vdp + 8 + j;
    const int m1 = ((d1 ^ (d1 >> 4)) & 7) << 3;
    f16x2 p1; p1[0] = va1[j]; p1[1] = vb1[j];
    *(f16x2*)(vsb + d1 * 64 + (vsp ^ m1)) = p1;
  }
}

// ---------------- flash attention: paired q-tiles, dbuf K/V, swizzled LDS ----------------
// grid (16 pairs, 16 bh), 256 threads. Block p: qt = p, then qt = 31-p (uniform 33 kv-tiles).
__global__ __launch_bounds__(256) void attn_kernel(
    const f16* __restrict__ Qs, const f16* __restrict__ Kq, const f16* __restrict__ Vq,
    float* __restrict__ X) {
  __shared__ f16 Ks[2][64 * 128];   // rows 256B; element (r,c) at r*128 + (c ^ ((r&7)<<3))
  __shared__ f16 Vs[2][128 * 64];   // V^T: (d,s) at d*64 + (s ^ (((d^(d>>4))&7)<<3))
  __shared__ f16 Ps[4][16 * 72];
  const int pr = blockIdx.x, bh = blockIdx.y;
  const int b = bh >> 2, h = bh & 3;
  const int t = threadIdx.x, wave = t >> 6, lane = t & 63;
  const int lg = lane >> 4, ln = lane & 15;
  const size_t base = (size_t)b * 2048 * 512 + h * 128;

  // K staging: pre-swizzled global source (LDS dest linear per rule #21)
  const int krow16 = wave * 4 + (lane >> 4);                       // row within 16-row issue
  const int kcol = ((lane & 15) * 8) ^ ((krow16 & 7) << 3);
  const f16* gK0 = Kq + base + (size_t)krow16 * 512 + kcol;
  // V loads (row-major), transposed into Vs via registers
  const int vsp = (t >> 3) * 2, vdp = (t & 7) * 16;
  const f16* gV0 = Vq + base + (size_t)vsp * 512 + vdp;

  for (int pass = 0; pass < 2; ++pass) {
    const int qt = pass ? (31 - pr) : pr;
    const int nt = qt + 1;
    f16x8 qf[4];
    {
      const int qrow = qt * 64 + wave * 16 + ln;
      const f16* qp = Qs + base + (size_t)qrow * 512 + lg * 8;
#pragma unroll
      for (int ks = 0; ks < 4; ks++) qf[ks] = *(const f16x8*)(qp + ks * 32);
    }
    f32x4 o[8] = {};
    float m_r[4], l_r[4];
#pragma unroll
    for (int r = 0; r < 4; r++) { m_r[r] = -1e30f; l_r[r] = 0.f; }

    f16x8 va0, va1, vb0, vb1;
    // prologue: tile 0 -> buf 0
    stage_k((char*)&Ks[0][0], gK0, wave);
    {
      const f16* gv = gV0;
      va0 = *(const f16x8*)(gv);       va1 = *(const f16x8*)(gv + 8);
      vb0 = *(const f16x8*)(gv + 512); vb1 = *(const f16x8*)(gv + 520);
    }
    write_v(&Vs[0][0], vsp, vdp, va0, va1, vb0, vb1);
    __syncthreads();

    for (int ti = 0; ti < nt; ++ti) {
      const int buf = ti & 1, nbuf = buf ^ 1;
      const bool pf = (ti + 1 < nt);
      if (pf) {
        stage_k((char*)&Ks[nbuf][0], gK0 + (size_t)(ti + 1) * 64 * 512, wave);
        const f16* gv = gV0 + (size_t)(ti + 1) * 64 * 512;
        va0 = *(const f16x8*)(gv);       va1 = *(const f16x8*)(gv + 8);
        vb0 = *(const f16x8*)(gv + 512); vb1 = *(const f16x8*)(gv + 520);
      }
      const int s0 = ti * 64;
      // S = Q K^T
      f32x4 sacc[4] = {};
      __builtin_amdgcn_s_setprio(1);
#pragma unroll
      for (int ks = 0; ks < 4; ks++)
#pragma unroll
        for (int fc = 0; fc < 4; fc++) {
          const int row = fc * 16 + ln;
          f16x8 bf = *(const f16x8*)(&Ks[buf][row * 128 + ((ks * 32 + lg * 8) ^ ((ln & 7) << 3))]);
          sacc[fc] = __builtin_amdgcn_mfma_f32_16x16x32_f16(qf[ks], bf, sacc[fc], 0, 0, 0);
        }
      __builtin_amdgcn_s_setprio(0);
      if (ti == nt - 1) {  // diagonal tile: causal mask
        const int rbase = qt * 64 + wave * 16 + lg * 4;
#pragma unroll
        for (int fc = 0; fc < 4; fc++) {
          const int col = s0 + fc * 16 + ln;
#pragma unroll
          for (int r = 0; r < 4; r++)
            if (col > rbase + r) sacc[fc][r] = -1e30f;
        }
      }
      // online softmax (rows across the 16-lane group)
      float tm[4];
#pragma unroll
      for (int r = 0; r < 4; r++)
        tm[r] = fmaxf(fmaxf(sacc[0][r], sacc[1][r]), fmaxf(sacc[2][r], sacc[3][r]));
#pragma unroll
      for (int r = 0; r < 4; r++) {
#pragma unroll
        for (int msk = 1; msk < 16; msk <<= 1) tm[r] = fmaxf(tm[r], __shfl_xor(tm[r], msk));
      }
      float al[4], ps[4];
#pragma unroll
      for (int r = 0; r < 4; r++) {
        const float mn = fmaxf(m_r[r], tm[r]);
        al[r] = __expf(m_r[r] - mn);
        m_r[r] = mn;
        ps[r] = 0.f;
      }
#pragma unroll
      for (int fc = 0; fc < 4; fc++)
#pragma unroll
        for (int r = 0; r < 4; r++) {
          const float p = __expf(sacc[fc][r] - m_r[r]);
          ps[r] += p;
          Ps[wave][(lg * 4 + r) * 72 + fc * 16 + ln] = (f16)p;
        }
#pragma unroll
      for (int r = 0; r < 4; r++) {
#pragma unroll
        for (int msk = 1; msk < 16; msk <<= 1) ps[r] += __shfl_xor(ps[r], msk);
        l_r[r] = l_r[r] * al[r] + ps[r];
      }
#pragma unroll
      for (int fc2 = 0; fc2 < 8; fc2++)
#pragma unroll
        for (int r = 0; r < 4; r++) o[fc2][r] *= al[r];
      // PV: O += P[16x64] . V[64x128]  (B-operand from swizzled V^T)
      __builtin_amdgcn_s_setprio(1);
#pragma unroll
      for (int ks2 = 0; ks2 < 2; ks2++) {
        f16x8 pa = *(const f16x8*)(&Ps[wave][ln * 72 + ks2 * 32 + lg * 8]);
#pragma unroll
        for (int fc2 = 0; fc2 < 8; fc2++) {
          const int d = fc2 * 16 + ln;
          f16x8 vbf = *(const f16x8*)(&Vs[buf][d * 64 +
                          ((ks2 * 32 + lg * 8) ^ (((ln ^ fc2) & 7) << 3))]);
          o[fc2] = __builtin_amdgcn_mfma_f32_16x16x32_f16(pa, vbf, o[fc2], 0, 0, 0);
        }
      }
      __builtin_amdgcn_s_setprio(0);
      if (pf) write_v(&Vs[nbuf][0], vsp, vdp, va0, va1, vb0, vb1);
      __syncthreads();
    }
    const int rbase = qt * 64 + wave * 16 + lg * 4;
#pragma unroll
    for (int r = 0; r < 4; r++) {
      const float inv = 1.0f / l_r[r];
      float* xp = X + ((size_t)b * 2048 + rbase + r) * 512 + h * 128 + ln;
#pragma unroll
      for (int fc2 = 0; fc2 < 8; fc2++) xp[fc2 * 16] = o[fc2][r] * inv;
    }
  }
}

// ---------------- LayerNorm(512) + act_quant fused ----------------
__global__ __launch_bounds__(256) void ln_quant(const float* __restrict__ X,
                                                const float* __restrict__ gamma,
                                                const float* __restrict__ beta,
                                                f16* __restrict__ Q, float* __restrict__ deq) {
  const size_t tok = blockIdx.x;
  const int t = threadIdx.x;
  const float* x = X + tok * 512;
  float2 v = *(const float2*)(x + t * 2);
  float s = v.x + v.y, sq = v.x * v.x + v.y * v.y;
  s = wave_red_sum(s);
  sq = wave_red_sum(sq);
  __shared__ float rs[4], rq[4], rm[4];
  const int wave = t >> 6, lane = t & 63;
  if (lane == 0) { rs[wave] = s; rq[wave] = sq; }
  __syncthreads();
  s = rs[0] + rs[1] + rs[2] + rs[3];
  sq = rq[0] + rq[1] + rq[2] + rq[3];
  const float mean = s * (1.0f / 512.0f);
  const float var = sq * (1.0f / 512.0f) - mean * mean;
  const float inv = 1.0f / sqrtf(var + 1e-5f);
  float2 g = *(const float2*)(gamma + t * 2);
  float2 be = *(const float2*)(beta + t * 2);
  const float t0 = (v.x - mean) * inv * g.x + be.x;
  const float t1 = (v.y - mean) * inv * g.y + be.y;
  float amax = fmaxf(fabsf(t0), fabsf(t1));
  amax = wave_red_max(amax);
  if (lane == 0) rm[wave] = amax;
  __syncthreads();
  amax = fmaxf(fmaxf(rm[0], rm[1]), fmaxf(rm[2], rm[3]));
  const float scale = 127.0f / fmaxf(amax, 1e-5f);
  f16x2 q;
  q[0] = (f16)fminf(fmaxf(rintf(t0 * scale), -128.f), 127.f);
  q[1] = (f16)fminf(fmaxf(rintf(t1 * scale), -128.f), 127.f);
  *(f16x2*)(Q + tok * 512 + t * 2) = q;
  if (t == 0) deq[tok] = 1.0f / scale;
}

// ---------------- launch ----------------
extern "C" void kernel_launch(void* const* d_in, const int* in_sizes, int n_in,
                              void* d_out, int out_size, void* d_ws, size_t ws_size,
                              hipStream_t stream) {
  const float* query = (const float*)d_in[0];
  const float* key   = (const float*)d_in[1];
  const float* value = (const float*)d_in[2];
  const float* Wq = (const float*)d_in[3];
  const float* bq = (const float*)d_in[4];
  const float* Wk = (const float*)d_in[5];
  const float* bk = (const float*)d_in[6];
  const float* Wv = (const float*)d_in[7];
  const float* bv = (const float*)d_in[8];
  const float* Wo = (const float*)d_in[9];
  const float* bo = (const float*)d_in[10];
  const float* gamma = (const float*)d_in[11];
  const float* beta  = (const float*)d_in[12];

  char* ws = (char*)d_ws;
  size_t off = 0;
  auto alloc = [&](size_t bytes) {
    char* p = ws + off;
    off = (off + bytes + 255) & ~(size_t)255;
    return p;
  };
  float* partial = (float*)alloc(1024 * 4);
  float* scales  = (float*)alloc(8 * 4);
  float* bqe     = (float*)alloc(512 * 4);
  f16* Wqe = (f16*)alloc((size_t)512 * 2048 * 2);
  f16* Wk8 = (f16*)alloc((size_t)512 * 2048 * 2);
  f16* Wv8 = (f16*)alloc((size_t)512 * 2048 * 2);
  f16* Wo8 = (f16*)alloc((size_t)2048 * 512 * 2);
  f16* a8v = (f16*)alloc((size_t)8192 * 2048 * 2);
  float* deq3 = (float*)alloc(3 * 8192 * 4);
  float* deqO = (float*)alloc(8192 * 4);
  f16* qs = (f16*)alloc((size_t)8192 * 512 * 2);
  f16* kq = (f16*)alloc((size_t)8192 * 512 * 2);
  f16* vq = (f16*)alloc((size_t)8192 * 512 * 2);
  float* x = (float*)alloc((size_t)8192 * 512 * 4);
  f16* a8o = (f16*)alloc((size_t)8192 * 512 * 2);
  (void)ws_size; (void)in_sizes; (void)n_in; (void)out_size;

  // a8 buffers for query/key live inside d_out (64 MB, dead until final GEMM)
  f16* a8q = (f16*)d_out;
  f16* a8k = (f16*)d_out + (size_t)8192 * 2048;

  // weight scales + quantization
  absum_partial<<<1024, 256, 0, stream>>>(Wq, Wk, Wv, Wo, partial);
  absum_final<<<1, 256, 0, stream>>>(partial, scales);
  quant_wq_eff<<<1024, 256, 0, stream>>>(Wq, Wqe, scales);
  bq_eff_kernel<<<2, 256, 0, stream>>>(bq, bqe);
  quant_w_ternary<<<1024, 256, 0, stream>>>(Wk, Wk8, scales, 1, 1048576);
  quant_w_ternary<<<1024, 256, 0, stream>>>(Wv, Wv8, scales, 2, 1048576);
  quant_w_ternary<<<1024, 256, 0, stream>>>(Wo, Wo8, scales, 3, 1048576);

  // activation quant (q,k,v fused) then fused QKV projection
  quant_act3<<<dim3(8192, 3), 256, 0, stream>>>(query, key, value, a8q, a8k, a8v, deq3);
  gemm_qkv<<<dim3(4, 64, 3), 256, 0, stream>>>(a8q, a8k, a8v, Wqe, Wk8, Wv8, deq3, scales,
                                               bqe, bk, bv, qs, kq, vq);

  // attention (paired causal tiles)
  attn_kernel<<<dim3(16, 16), 256, 0, stream>>>(qs, kq, vq, x);

  // layernorm + quant + output projection
  ln_quant<<<8192, 256, 0, stream>>>(x, gamma, beta, a8o, deqO);
  gemm_o<<<dim3(16, 64), 256, 0, stream>>>(a8o, Wo8, deqO, scales, bo, (float*)d_out);
}

// Round 4
// 408.695 us; speedup vs baseline: 1.5317x; 1.1852x over previous
//
#include <hip/hip_runtime.h>
#include <hip/hip_fp16.h>

typedef _Float16 f16;
typedef __attribute__((ext_vector_type(8))) _Float16 f16x8;
typedef __attribute__((ext_vector_type(4))) _Float16 f16x4;
typedef __attribute__((ext_vector_type(2))) _Float16 f16x2;
typedef __attribute__((ext_vector_type(4))) float f32x4;
typedef __attribute__((ext_vector_type(4))) int i32x4;

#define AS1(p) ((__attribute__((address_space(1))) char*)(p))
#define AS3(p) ((__attribute__((address_space(3))) char*)(p))

static __device__ __forceinline__ float wave_red_sum(float v) {
#pragma unroll
  for (int m = 1; m < 64; m <<= 1) v += __shfl_xor(v, m);
  return v;
}
static __device__ __forceinline__ float wave_red_max(float v) {
#pragma unroll
  for (int m = 1; m < 64; m <<= 1) v = fmaxf(v, __shfl_xor(v, m));
  return v;
}
static __device__ __forceinline__ int pack4(int q0, int q1, int q2, int q3) {
  return (q0 & 255) | ((q1 & 255) << 8) | ((q2 & 255) << 16) | ((q3 & 255) << 24);
}

// ---------------- weight scale: sum |W| (deterministic 2-stage) ----------------
__global__ __launch_bounds__(256) void absum_partial(
    const float* __restrict__ Wq, const float* __restrict__ Wk,
    const float* __restrict__ Wv, const float* __restrict__ Wo,
    float* __restrict__ partial) {
  const int w = blockIdx.x >> 8;
  const int lb = blockIdx.x & 255;
  const float* W = (w == 0) ? Wq : (w == 1) ? Wk : (w == 2) ? Wv : Wo;
  const int per_block = (w == 0) ? (4194304 >> 8) : (1048576 >> 8);
  const float* base = W + (size_t)lb * per_block;
  float s = 0.f;
  for (int i = threadIdx.x * 4; i < per_block; i += 256 * 4) {
    float4 v = *(const float4*)(base + i);
    s += fabsf(v.x) + fabsf(v.y) + fabsf(v.z) + fabsf(v.w);
  }
  s = wave_red_sum(s);
  __shared__ float red[4];
  const int wave = threadIdx.x >> 6, lane = threadIdx.x & 63;
  if (lane == 0) red[wave] = s;
  __syncthreads();
  if (threadIdx.x == 0) partial[blockIdx.x] = red[0] + red[1] + red[2] + red[3];
}

__global__ __launch_bounds__(256) void absum_final(const float* __restrict__ partial,
                                                   float* __restrict__ scales) {
  const int wave = threadIdx.x >> 6, lane = threadIdx.x & 63;
  const float* p = partial + wave * 256;
  float s = p[lane] + p[lane + 64] + p[lane + 128] + p[lane + 192];
  s = wave_red_sum(s);
  if (lane == 0) {
    const float cnt = (wave == 0) ? 4194304.f : 1048576.f;
    const float mean = s / cnt;
    const float mul = 1.0f / fmaxf(mean, 1e-5f);
    scales[wave] = mul;
    scales[4 + wave] = 1.0f / mul;
  }
}

// ---------------- ternary weight quantization (Wk, Wv, Wo fused; int8 out) ----------------
__global__ __launch_bounds__(256) void quant_w3(
    const float* __restrict__ Wk, const float* __restrict__ Wv, const float* __restrict__ Wo,
    char* __restrict__ Ok, char* __restrict__ Ov, char* __restrict__ Oo,
    const float* __restrict__ scales) {
  const int z = blockIdx.y;
  const float* W = z == 0 ? Wk : z == 1 ? Wv : Wo;
  char* O = z == 0 ? Ok : z == 1 ? Ov : Oo;
  const float mul = scales[1 + z];
  const int i = (blockIdx.x * 256 + threadIdx.x) * 8;
  float4 a = *(const float4*)(W + i);
  float4 b = *(const float4*)(W + i + 4);
  const int q0 = (int)fminf(fmaxf(rintf(a.x * mul), -1.f), 1.f);
  const int q1 = (int)fminf(fmaxf(rintf(a.y * mul), -1.f), 1.f);
  const int q2 = (int)fminf(fmaxf(rintf(a.z * mul), -1.f), 1.f);
  const int q3 = (int)fminf(fmaxf(rintf(a.w * mul), -1.f), 1.f);
  const int q4 = (int)fminf(fmaxf(rintf(b.x * mul), -1.f), 1.f);
  const int q5 = (int)fminf(fmaxf(rintf(b.y * mul), -1.f), 1.f);
  const int q6 = (int)fminf(fmaxf(rintf(b.z * mul), -1.f), 1.f);
  const int q7 = (int)fminf(fmaxf(rintf(b.w * mul), -1.f), 1.f);
  int2 p;
  p.x = pack4(q0, q1, q2, q3);
  p.y = pack4(q4, q5, q6, q7);
  *(int2*)(O + i) = p;
}

// Wq with group-sum folded: We[h*128+d][e] = sum_g tern(Wq[(h*4+g)*128+d][e]); int8 in [-4,4]
__global__ __launch_bounds__(256) void quant_wq_eff(const float* __restrict__ Wq,
                                                    char* __restrict__ We,
                                                    const float* __restrict__ scales) {
  const float mul = scales[0];
  const int idx = (blockIdx.x * 256 + threadIdx.x) * 4;
  const int j = idx >> 11, e = idx & 2047;
  const int h = j >> 7, d = j & 127;
  float a0 = 0, a1 = 0, a2 = 0, a3 = 0;
#pragma unroll
  for (int g = 0; g < 4; g++) {
    const float* src = Wq + (size_t)((h * 4 + g) * 128 + d) * 2048 + e;
    float4 v = *(const float4*)src;
    a0 += fminf(fmaxf(rintf(v.x * mul), -1.f), 1.f);
    a1 += fminf(fmaxf(rintf(v.y * mul), -1.f), 1.f);
    a2 += fminf(fmaxf(rintf(v.z * mul), -1.f), 1.f);
    a3 += fminf(fmaxf(rintf(v.w * mul), -1.f), 1.f);
  }
  *(int*)(We + idx) = pack4((int)a0, (int)a1, (int)a2, (int)a3);
}

__global__ void bq_eff_kernel(const float* __restrict__ bq, float* __restrict__ be) {
  const int j = blockIdx.x * 256 + threadIdx.x;
  if (j >= 512) return;
  const int h = j >> 7, d = j & 127;
  float s = 0.f;
#pragma unroll
  for (int g = 0; g < 4; g++) s += bq[(h * 4 + g) * 128 + d];
  be[j] = s;
}

// ---------------- per-token activation quantization, 3 tensors fused; int8 out ----------------
__global__ __launch_bounds__(256) void quant_act3(
    const float* __restrict__ Xq, const float* __restrict__ Xk, const float* __restrict__ Xv,
    char* __restrict__ Aq, char* __restrict__ Ak, char* __restrict__ Av,
    float* __restrict__ deq3) {
  const int which = blockIdx.y;
  const float* X = which == 0 ? Xq : which == 1 ? Xk : Xv;
  char* Q = which == 0 ? Aq : which == 1 ? Ak : Av;
  float* deq = deq3 + which * 8192;
  const size_t tok = blockIdx.x;
  const float* x = X + tok * 2048;
  const int t = threadIdx.x;
  float4 v0 = *(const float4*)(x + t * 8);
  float4 v1 = *(const float4*)(x + t * 8 + 4);
  float amax = fmaxf(fmaxf(fmaxf(fabsf(v0.x), fabsf(v0.y)), fmaxf(fabsf(v0.z), fabsf(v0.w))),
                     fmaxf(fmaxf(fabsf(v1.x), fabsf(v1.y)), fmaxf(fabsf(v1.z), fabsf(v1.w))));
  amax = wave_red_max(amax);
  __shared__ float red[4];
  const int wave = t >> 6, lane = t & 63;
  if (lane == 0) red[wave] = amax;
  __syncthreads();
  amax = fmaxf(fmaxf(red[0], red[1]), fmaxf(red[2], red[3]));
  const float scale = 127.0f / fmaxf(amax, 1e-5f);
  const int q0 = (int)fminf(fmaxf(rintf(v0.x * scale), -128.f), 127.f);
  const int q1 = (int)fminf(fmaxf(rintf(v0.y * scale), -128.f), 127.f);
  const int q2 = (int)fminf(fmaxf(rintf(v0.z * scale), -128.f), 127.f);
  const int q3 = (int)fminf(fmaxf(rintf(v0.w * scale), -128.f), 127.f);
  const int q4 = (int)fminf(fmaxf(rintf(v1.x * scale), -128.f), 127.f);
  const int q5 = (int)fminf(fmaxf(rintf(v1.y * scale), -128.f), 127.f);
  const int q6 = (int)fminf(fmaxf(rintf(v1.z * scale), -128.f), 127.f);
  const int q7 = (int)fminf(fmaxf(rintf(v1.w * scale), -128.f), 127.f);
  int2 p;
  p.x = pack4(q0, q1, q2, q3);
  p.y = pack4(q4, q5, q6, q7);
  *(int2*)(Q + tok * 2048 + t * 8) = p;
  if (t == 0) deq[tok] = 1.0f / scale;
}

// ---------------- i8 GEMM core: 128x128 tile, BK=64, dbuf LDS, swizzled ----------------
// LDS layout: As[buf][row][c16] where stored c16 holds logical c16 ^ ((row>>1)&3)  (16B units)
static __device__ __forceinline__ void stage_i8(const char* src, char* dst, int wave, int K) {
  __builtin_amdgcn_global_load_lds(AS1(src), AS3(dst + wave * 1024), 16, 0, 0);
  __builtin_amdgcn_global_load_lds(AS1(src + (size_t)64 * K), AS3(dst + 4096 + wave * 1024), 16, 0, 0);
}

template <typename OutT>
static __device__ __forceinline__ void gemm_core_i8(
    const char* __restrict__ A, const char* __restrict__ W,
    const float* __restrict__ deqA, const float dW,
    const float* __restrict__ bias, OutT* __restrict__ C,
    const int N, const int K, const float out_scale, const int bm, const int bn,
    char* As, char* Bs) {
  const int t = threadIdx.x;
  const int wave = t >> 6, lane = t & 63;
  const int lg = lane >> 4, ln = lane & 15;
  const int wr = (wave >> 1) * 64, wc = (wave & 1) * 64;
  i32x4 acc[4][4] = {};
  // staging: dest (row = t>>2 (+64), c16 = t&3); pre-swizzled source column
  const int swS = ((t & 3) ^ ((t >> 3) & 3)) * 16;
  const char* gA = A + (size_t)(bm * 128 + (t >> 2)) * K + swS;
  const char* gB = W + (size_t)(bn * 128 + (t >> 2)) * K + swS;
  // fragment read: logical c16 = lg at stored lg ^ ((row>>1)&3), row = 16m + ln
  const int swR = (lg ^ ((ln >> 1) & 3)) * 16;
  const int NI = K >> 6;

  stage_i8(gA, As, wave, K);
  stage_i8(gB, Bs, wave, K);
  __syncthreads();
  int buf = 0;
  for (int it = 0; it < NI; ++it) {
    if (it + 1 < NI) {  // issue next tile into the other buffer; overlaps MFMA below
      stage_i8(gA + (it + 1) * 64, As + ((buf ^ 1) << 13), wave, K);
      stage_i8(gB + (it + 1) * 64, Bs + ((buf ^ 1) << 13), wave, K);
    }
    i32x4 af[4], bf[4];
#pragma unroll
    for (int fr = 0; fr < 4; fr++)
      af[fr] = *(const i32x4*)(As + (buf << 13) + (wr + fr * 16 + ln) * 64 + swR);
#pragma unroll
    for (int fc = 0; fc < 4; fc++)
      bf[fc] = *(const i32x4*)(Bs + (buf << 13) + (wc + fc * 16 + ln) * 64 + swR);
    __builtin_amdgcn_s_setprio(1);
#pragma unroll
    for (int fr = 0; fr < 4; fr++)
#pragma unroll
      for (int fc = 0; fc < 4; fc++)
        acc[fr][fc] = __builtin_amdgcn_mfma_i32_16x16x64_i8(af[fr], bf[fc], acc[fr][fc], 0, 0, 0);
    __builtin_amdgcn_s_setprio(0);
    __syncthreads();  // drains my next-tile loads + everyone done reading buf
    buf ^= 1;
  }
#pragma unroll
  for (int fr = 0; fr < 4; fr++) {
#pragma unroll
    for (int r = 0; r < 4; r++) {
      const int grow = bm * 128 + wr + fr * 16 + lg * 4 + r;
      const float dA = deqA[grow] * dW;
#pragma unroll
      for (int fc = 0; fc < 4; fc++) {
        const int gcol = bn * 128 + wc + fc * 16 + ln;
        C[(size_t)grow * N + gcol] = (OutT)(((float)acc[fr][fc][r] * dA + bias[gcol]) * out_scale);
      }
    }
  }
}

// fused QKV projection: grid (4, 64, 3), XCD-chunked remap (768 blocks, 96/XCD)
__global__ __launch_bounds__(256) void gemm_qkv(
    const char* __restrict__ Aq, const char* __restrict__ Ak, const char* __restrict__ Av,
    const char* __restrict__ Wqe, const char* __restrict__ Wk8, const char* __restrict__ Wv8,
    const float* __restrict__ deq3, const float* __restrict__ scales,
    const float* __restrict__ bqe, const float* __restrict__ bk, const float* __restrict__ bv,
    f16* __restrict__ Cq, f16* __restrict__ Ck, f16* __restrict__ Cv) {
  __shared__ __align__(16) char As[2][8192];
  __shared__ __align__(16) char Bs[2][8192];
  const int orig = blockIdx.x + (blockIdx.y << 2) + (blockIdx.z << 8);
  const int wk = ((orig & 7) * 96) + (orig >> 3);
  const int z = wk >> 8, rem = wk & 255, bm = rem >> 2, bn = rem & 3;
  const char* A = z == 0 ? Aq : z == 1 ? Ak : Av;
  const char* W = z == 0 ? Wqe : z == 1 ? Wk8 : Wv8;
  const float* bias = z == 0 ? bqe : z == 1 ? bk : bv;
  f16* C = z == 0 ? Cq : z == 1 ? Ck : Cv;
  gemm_core_i8<f16>(A, W, deq3 + z * 8192, scales[4 + z], bias, C,
                    512, 2048, z == 0 ? (1.0f / 128.0f) : 1.0f, bm, bn, &As[0][0], &Bs[0][0]);
}

// output projection: grid (16, 64), remap (1024 blocks, 128/XCD)
__global__ __launch_bounds__(256) void gemm_o(
    const char* __restrict__ A, const char* __restrict__ W,
    const float* __restrict__ deqA, const float* __restrict__ scales,
    const float* __restrict__ bias, float* __restrict__ C) {
  __shared__ __align__(16) char As[2][8192];
  __shared__ __align__(16) char Bs[2][8192];
  const int orig = blockIdx.x + (blockIdx.y << 4);
  const int wk = ((orig & 7) * 128) + (orig >> 3);
  const int bm = wk >> 4, bn = wk & 15;
  gemm_core_i8<float>(A, W, deqA, scales[7], bias, C, 2048, 512, 1.0f, bm, bn,
                      &As[0][0], &Bs[0][0]);
}

// ---------------- flash attention helpers ----------------
static __device__ __forceinline__ void stage_k(char* ksb, const f16* src, int wave) {
#pragma unroll
  for (int i = 0; i < 4; i++)
    __builtin_amdgcn_global_load_lds(AS1(src + (size_t)i * 16 * 512),
                                     AS3(ksb + i * 4096 + wave * 1024), 16, 0, 0);
}

static __device__ __forceinline__ void write_v(f16* vsb, int vsp, int vdp,
                                               f16x8 va0, f16x8 va1, f16x8 vb0, f16x8 vb1) {
#pragma unroll
  for (int j = 0; j < 8; j++) {
    const int d0 = vdp + j;
    const int m0 = ((d0 ^ (d0 >> 4)) & 7) << 3;
    f16x2 p0; p0[0] = va0[j]; p0[1] = vb0[j];
    *(f16x2*)(vsb + d0 * 64 + (vsp ^ m0)) = p0;
    const int d1 = vdp + 8 + j;
    const int m1 = ((d1 ^ (d1 >> 4)) & 7) << 3;
    f16x2 p1; p1[0] = va1[j]; p1[1] = vb1[j];
    *(f16x2*)(vsb + d1 * 64 + (vsp ^ m1)) = p1;
  }
}

// ---------------- flash attention: paired q-tiles, dbuf K/V, swizzled LDS ----------------
// grid (16 pairs, 16 bh), 256 threads. Block p: qt = p, then qt = 31-p (uniform 33 kv-tiles).
__global__ __launch_bounds__(256) void attn_kernel(
    const f16* __restrict__ Qs, const f16* __restrict__ Kq, const f16* __restrict__ Vq,
    float* __restrict__ X) {
  __shared__ f16 Ks[2][64 * 128];   // rows 256B; element (r,c) at r*128 + (c ^ ((r&7)<<3))
  __shared__ f16 Vs[2][128 * 64];   // V^T: (d,s) at d*64 + (s ^ (((d^(d>>4))&7)<<3))
  __shared__ f16 Ps[4][16 * 72];
  const int pr = blockIdx.x, bh = blockIdx.y;
  const int b = bh >> 2, h = bh & 3;
  const int t = threadIdx.x, wave = t >> 6, lane = t & 63;
  const int lg = lane >> 4, ln = lane & 15;
  const size_t base = (size_t)b * 2048 * 512 + h * 128;

  const int krow16 = wave * 4 + (lane >> 4);
  const int kcol = ((lane & 15) * 8) ^ ((krow16 & 7) << 3);
  const f16* gK0 = Kq + base + (size_t)krow16 * 512 + kcol;
  const int vsp = (t >> 3) * 2, vdp = (t & 7) * 16;
  const f16* gV0 = Vq + base + (size_t)vsp * 512 + vdp;

  for (int pass = 0; pass < 2; ++pass) {
    const int qt = pass ? (31 - pr) : pr;
    const int nt = qt + 1;
    f16x8 qf[4];
    {
      const int qrow = qt * 64 + wave * 16 + ln;
      const f16* qp = Qs + base + (size_t)qrow * 512 + lg * 8;
#pragma unroll
      for (int ks = 0; ks < 4; ks++) qf[ks] = *(const f16x8*)(qp + ks * 32);
    }
    f32x4 o[8] = {};
    float m_r[4], l_r[4];
#pragma unroll
    for (int r = 0; r < 4; r++) { m_r[r] = -1e30f; l_r[r] = 0.f; }

    f16x8 va0, va1, vb0, vb1;
    stage_k((char*)&Ks[0][0], gK0, wave);
    {
      const f16* gv = gV0;
      va0 = *(const f16x8*)(gv);       va1 = *(const f16x8*)(gv + 8);
      vb0 = *(const f16x8*)(gv + 512); vb1 = *(const f16x8*)(gv + 520);
    }
    write_v(&Vs[0][0], vsp, vdp, va0, va1, vb0, vb1);
    __syncthreads();

    for (int ti = 0; ti < nt; ++ti) {
      const int buf = ti & 1, nbuf = buf ^ 1;
      const bool pf = (ti + 1 < nt);
      if (pf) {
        stage_k((char*)&Ks[nbuf][0], gK0 + (size_t)(ti + 1) * 64 * 512, wave);
        const f16* gv = gV0 + (size_t)(ti + 1) * 64 * 512;
        va0 = *(const f16x8*)(gv);       va1 = *(const f16x8*)(gv + 8);
        vb0 = *(const f16x8*)(gv + 512); vb1 = *(const f16x8*)(gv + 520);
      }
      const int s0 = ti * 64;
      f32x4 sacc[4] = {};
      __builtin_amdgcn_s_setprio(1);
#pragma unroll
      for (int ks = 0; ks < 4; ks++)
#pragma unroll
        for (int fc = 0; fc < 4; fc++) {
          const int row = fc * 16 + ln;
          f16x8 bf = *(const f16x8*)(&Ks[buf][row * 128 + ((ks * 32 + lg * 8) ^ ((ln & 7) << 3))]);
          sacc[fc] = __builtin_amdgcn_mfma_f32_16x16x32_f16(qf[ks], bf, sacc[fc], 0, 0, 0);
        }
      __builtin_amdgcn_s_setprio(0);
      if (ti == nt - 1) {
        const int rbase = qt * 64 + wave * 16 + lg * 4;
#pragma unroll
        for (int fc = 0; fc < 4; fc++) {
          const int col = s0 + fc * 16 + ln;
#pragma unroll
          for (int r = 0; r < 4; r++)
            if (col > rbase + r) sacc[fc][r] = -1e30f;
        }
      }
      float tm[4];
#pragma unroll
      for (int r = 0; r < 4; r++)
        tm[r] = fmaxf(fmaxf(sacc[0][r], sacc[1][r]), fmaxf(sacc[2][r], sacc[3][r]));
#pragma unroll
      for (int r = 0; r < 4; r++) {
#pragma unroll
        for (int msk = 1; msk < 16; msk <<= 1) tm[r] = fmaxf(tm[r], __shfl_xor(tm[r], msk));
      }
      float al[4], ps[4];
#pragma unroll
      for (int r = 0; r < 4; r++) {
        const float mn = fmaxf(m_r[r], tm[r]);
        al[r] = __expf(m_r[r] - mn);
        m_r[r] = mn;
        ps[r] = 0.f;
      }
#pragma unroll
      for (int fc = 0; fc < 4; fc++)
#pragma unroll
        for (int r = 0; r < 4; r++) {
          const float p = __expf(sacc[fc][r] - m_r[r]);
          ps[r] += p;
          Ps[wave][(lg * 4 + r) * 72 + fc * 16 + ln] = (f16)p;
        }
#pragma unroll
      for (int r = 0; r < 4; r++) {
#pragma unroll
        for (int msk = 1; msk < 16; msk <<= 1) ps[r] += __shfl_xor(ps[r], msk);
        l_r[r] = l_r[r] * al[r] + ps[r];
      }
#pragma unroll
      for (int fc2 = 0; fc2 < 8; fc2++)
#pragma unroll
        for (int r = 0; r < 4; r++) o[fc2][r] *= al[r];
      __builtin_amdgcn_s_setprio(1);
#pragma unroll
      for (int ks2 = 0; ks2 < 2; ks2++) {
        f16x8 pa = *(const f16x8*)(&Ps[wave][ln * 72 + ks2 * 32 + lg * 8]);
#pragma unroll
        for (int fc2 = 0; fc2 < 8; fc2++) {
          const int d = fc2 * 16 + ln;
          f16x8 vbf = *(const f16x8*)(&Vs[buf][d * 64 +
                          ((ks2 * 32 + lg * 8) ^ (((ln ^ fc2) & 7) << 3))]);
          o[fc2] = __builtin_amdgcn_mfma_f32_16x16x32_f16(pa, vbf, o[fc2], 0, 0, 0);
        }
      }
      __builtin_amdgcn_s_setprio(0);
      if (pf) write_v(&Vs[nbuf][0], vsp, vdp, va0, va1, vb0, vb1);
      __syncthreads();
    }
    const int rbase = qt * 64 + wave * 16 + lg * 4;
#pragma unroll
    for (int r = 0; r < 4; r++) {
      const float inv = 1.0f / l_r[r];
      float* xp = X + ((size_t)b * 2048 + rbase + r) * 512 + h * 128 + ln;
#pragma unroll
      for (int fc2 = 0; fc2 < 8; fc2++) xp[fc2 * 16] = o[fc2][r] * inv;
    }
  }
}

// ---------------- LayerNorm(512) + act_quant fused; int8 out ----------------
__global__ __launch_bounds__(256) void ln_quant(const float* __restrict__ X,
                                                const float* __restrict__ gamma,
                                                const float* __restrict__ beta,
                                                char* __restrict__ Q, float* __restrict__ deq) {
  const size_t tok = blockIdx.x;
  const int t = threadIdx.x;
  const float* x = X + tok * 512;
  float2 v = *(const float2*)(x + t * 2);
  float s = v.x + v.y, sq = v.x * v.x + v.y * v.y;
  s = wave_red_sum(s);
  sq = wave_red_sum(sq);
  __shared__ float rs[4], rq[4], rm[4];
  const int wave = t >> 6, lane = t & 63;
  if (lane == 0) { rs[wave] = s; rq[wave] = sq; }
  __syncthreads();
  s = rs[0] + rs[1] + rs[2] + rs[3];
  sq = rq[0] + rq[1] + rq[2] + rq[3];
  const float mean = s * (1.0f / 512.0f);
  const float var = sq * (1.0f / 512.0f) - mean * mean;
  const float inv = 1.0f / sqrtf(var + 1e-5f);
  float2 g = *(const float2*)(gamma + t * 2);
  float2 be = *(const float2*)(beta + t * 2);
  const float t0 = (v.x - mean) * inv * g.x + be.x;
  const float t1 = (v.y - mean) * inv * g.y + be.y;
  float amax = fmaxf(fabsf(t0), fabsf(t1));
  amax = wave_red_max(amax);
  if (lane == 0) rm[wave] = amax;
  __syncthreads();
  amax = fmaxf(fmaxf(rm[0], rm[1]), fmaxf(rm[2], rm[3]));
  const float scale = 127.0f / fmaxf(amax, 1e-5f);
  const int q0 = (int)fminf(fmaxf(rintf(t0 * scale), -128.f), 127.f);
  const int q1 = (int)fminf(fmaxf(rintf(t1 * scale), -128.f), 127.f);
  *(unsigned short*)(Q + tok * 512 + t * 2) = (unsigned short)((q0 & 255) | ((q1 & 255) << 8));
  if (t == 0) deq[tok] = 1.0f / scale;
}

// ---------------- launch ----------------
extern "C" void kernel_launch(void* const* d_in, const int* in_sizes, int n_in,
                              void* d_out, int out_size, void* d_ws, size_t ws_size,
                              hipStream_t stream) {
  const float* query = (const float*)d_in[0];
  const float* key   = (const float*)d_in[1];
  const float* value = (const float*)d_in[2];
  const float* Wq = (const float*)d_in[3];
  const float* bq = (const float*)d_in[4];
  const float* Wk = (const float*)d_in[5];
  const float* bk = (const float*)d_in[6];
  const float* Wv = (const float*)d_in[7];
  const float* bv = (const float*)d_in[8];
  const float* Wo = (const float*)d_in[9];
  const float* bo = (const float*)d_in[10];
  const float* gamma = (const float*)d_in[11];
  const float* beta  = (const float*)d_in[12];

  char* ws = (char*)d_ws;
  size_t off = 0;
  auto alloc = [&](size_t bytes) {
    char* p = ws + off;
    off = (off + bytes + 255) & ~(size_t)255;
    return p;
  };
  float* partial = (float*)alloc(1024 * 4);
  float* scales  = (float*)alloc(8 * 4);
  float* bqe     = (float*)alloc(512 * 4);
  char* Wqe = alloc((size_t)512 * 2048);
  char* Wk8 = alloc((size_t)512 * 2048);
  char* Wv8 = alloc((size_t)512 * 2048);
  char* Wo8 = alloc((size_t)2048 * 512);
  char* a8v = alloc((size_t)8192 * 2048);
  float* deq3 = (float*)alloc(3 * 8192 * 4);
  float* deqO = (float*)alloc(8192 * 4);
  f16* qs = (f16*)alloc((size_t)8192 * 512 * 2);
  f16* kq = (f16*)alloc((size_t)8192 * 512 * 2);
  f16* vq = (f16*)alloc((size_t)8192 * 512 * 2);
  float* x = (float*)alloc((size_t)8192 * 512 * 4);
  char* a8o = alloc((size_t)8192 * 512);
  (void)ws_size; (void)in_sizes; (void)n_in; (void)out_size;

  // a8 buffers for query/key live inside d_out (64 MB, dead until final GEMM)
  char* a8q = (char*)d_out;
  char* a8k = (char*)d_out + (size_t)8192 * 2048;

  // weight scales + quantization
  absum_partial<<<1024, 256, 0, stream>>>(Wq, Wk, Wv, Wo, partial);
  absum_final<<<1, 256, 0, stream>>>(partial, scales);
  quant_wq_eff<<<1024, 256, 0, stream>>>(Wq, Wqe, scales);
  bq_eff_kernel<<<2, 256, 0, stream>>>(bq, bqe);
  quant_w3<<<dim3(512, 3), 256, 0, stream>>>(Wk, Wv, Wo, Wk8, Wv8, Wo8, scales);

  // activation quant (q,k,v fused) then fused QKV projection
  quant_act3<<<dim3(8192, 3), 256, 0, stream>>>(query, key, value, a8q, a8k, a8v, deq3);
  gemm_qkv<<<dim3(4, 64, 3), 256, 0, stream>>>(a8q, a8k, a8v, Wqe, Wk8, Wv8, deq3, scales,
                                               bqe, bk, bv, qs, kq, vq);

  // attention (paired causal tiles)
  attn_kernel<<<dim3(16, 16), 256, 0, stream>>>(qs, kq, vq, x);

  // layernorm + quant + output projection
  ln_quant<<<8192, 256, 0, stream>>>(x, gamma, beta, a8o, deqO);
  gemm_o<<<dim3(16, 64), 256, 0, stream>>>(a8o, Wo8, deqO, scales, bo, (float*)d_out);
}